// Round 8
// baseline (218.759 us; speedup 1.0000x reference)
//
#include <hip/hip_runtime.h>

#define BATCH 8
#define CCH   128
#define DQK   16
#define HW    4096   // N = H*W
#define LOG2E 1.44269504088896340736f
#define KTS   24     // kT padded row stride in ushorts (48B rows)
#define WTS   136    // W padded row stride in ushorts (272B rows)
#define WGRAN 2816   // W staged granules (2720 real, padded to 11*256)
#define VTP   72     // vt transpose-buffer row stride (144B, 16B-mult)

typedef __attribute__((ext_vector_type(8))) short bf16x8;   // 8 bf16 = 4 VGPRs
typedef __attribute__((ext_vector_type(4))) float f32x4;

// pack two f32 -> packed bf16 pair (lo, hi), single HW instruction
__device__ __forceinline__ unsigned cvt_pk_bf16(float lo, float hi) {
    unsigned r;
    asm("v_cvt_pk_bf16_f32 %0, %1, %2" : "=v"(r) : "v"(lo), "v"(hi));
    return r;
}

// async global->LDS, 16B per lane. LDS dest must be linear (base + lane*16)
// across the wave; global src is per-lane.
__device__ __forceinline__ void glds16(const void* gsrc, const void* lds) {
    auto* g = (const __attribute__((address_space(1))) unsigned int*)(unsigned long long)(uintptr_t)gsrc;
    auto* s = (__attribute__((address_space(3))) unsigned int*)(unsigned int)(uintptr_t)lds;
    __builtin_amdgcn_global_load_lds(g, s, 16, 0, 0);
}

// ------------------------------------------------------------------
// Kernel P: one-time W -> bf16 pre-convert into padded [160][WTS]
// layout (LOG2E folded into Wq rows). Pad cols zeroed.
// ------------------------------------------------------------------
__global__ __launch_bounds__(256) void prep_kernel(
    const float* __restrict__ Wq, const float* __restrict__ Wk,
    const float* __restrict__ Wv, ushort* __restrict__ Wpad)
{
    const int idx = blockIdx.x * 256 + threadIdx.x;
    if (idx >= 160 * (WTS / 2)) return;
    const int row = idx / (WTS / 2);
    const int c0  = (idx % (WTS / 2)) * 2;
    unsigned val = 0;
    if (c0 < CCH) {
        const float* src;
        float sc = 1.f;
        if (row < 16)       { src = Wq + row * CCH;        sc = LOG2E; }
        else if (row < 32)  { src = Wk + (row - 16) * CCH; }
        else                { src = Wv + (row - 32) * CCH; }
        val = cvt_pk_bf16(src[c0] * sc, src[c0 + 1] * sc);
    }
    *(unsigned*)&Wpad[row * WTS + c0] = val;
}

// ------------------------------------------------------------------
// Kernel A v2: q/k/v projections, ZERO scalar global traffic.
// grid = 512 x 256 (4 waves). Block owns 64 pixels of one batch.
//  - x tile (64px x 128c fp32, 32KB) staged via 8 coalesced glds16
//    per thread into linear [c][64px] LDS.
//  - W staged via 11 glds16/thread from pre-padded bf16 global.
//  - fragments built from LDS (scalar f32 reads + cvt_pk).
//  - 10 o-tiles x 4 k-steps = 40 MFMA per wave.
//  - v output transposed through LDS (overlaying x_l): scalar 2B
//    ds_writes -> barrier -> b128 reads -> 16B coalesced stores.
// q stored [b][px][16] (xLOG2E); kT stored [b][px][KTS]; v [b][c][px].
// ------------------------------------------------------------------
__global__ __launch_bounds__(256) void qkv_kernel(
    const float* __restrict__ x, const ushort* __restrict__ Wpad,
    const float* __restrict__ bq, const float* __restrict__ bk,
    const float* __restrict__ bv,
    ushort* __restrict__ qT, ushort* __restrict__ kT, ushort* __restrict__ v)
{
    const int blk = blockIdx.x;
    const int b   = blk >> 6;
    const int p0  = (blk & 63) << 6;
    const int t   = threadIdx.x;
    const int l   = t & 63;
    const int w   = t >> 6;
    const int lm  = l & 15;
    const int lg  = l >> 4;

    __shared__ __align__(16) float  x_l[CCH * 64];     // 32KB [c][64px] linear (glds)
    __shared__ __align__(16) ushort W_l[WGRAN * 8];    // 45KB

    // ---- stage x: 2048 granules (16B = 4px), fully coalesced DMA ----
#pragma unroll
    for (int i = 0; i < 8; i++) {
        const int idx = t + 256 * i;                   // c = idx>>4, px-quad = idx&15
        glds16(x + (size_t)b * CCH * HW + (size_t)(idx >> 4) * HW + p0 + (idx & 15) * 4,
               &x_l[idx * 4]);
    }
    // ---- stage W: 11 granules per thread, coalesced DMA ----
#pragma unroll
    for (int i = 0; i < 11; i++) {
        const int idx = t + 256 * i;
        glds16(Wpad + idx * 8, &W_l[idx * 8]);
    }
    __syncthreads();   // drains vmcnt(0): both stages complete

    // ---- B-frags from x_l: lane (lg,lm) needs x[c=ks*32+lg*8+r][px=16w+lm] ----
    bf16x8 bfrag[4];
#pragma unroll
    for (int ks = 0; ks < 4; ks++) {
        float xr[8];
#pragma unroll
        for (int r = 0; r < 8; r++)
            xr[r] = x_l[(ks * 32 + lg * 8 + r) * 64 + 16 * w + lm];
        unsigned u[4];
#pragma unroll
        for (int r = 0; r < 4; r++) u[r] = cvt_pk_bf16(xr[2 * r], xr[2 * r + 1]);
        bfrag[ks] = *(bf16x8*)u;
    }

    f32x4 acc[10];
#pragma unroll
    for (int ot = 0; ot < 10; ot++)
#pragma unroll
        for (int r = 0; r < 4; r++) acc[ot][r] = 0.f;

#pragma unroll
    for (int ot = 0; ot < 10; ot++) {
#pragma unroll
        for (int ks = 0; ks < 4; ks++) {
            const bf16x8 afrag = *(const bf16x8*)&W_l[(ot * 16 + lm) * WTS + ks * 32 + lg * 8];
            acc[ot] = __builtin_amdgcn_mfma_f32_16x16x32_bf16(afrag, bfrag[ks], acc[ot], 0, 0, 0);
        }
    }

    // ---- q / kT stores (small, direct) ----
    const int px_loc = 16 * w + lm;
    const int px     = p0 + px_loc;
    {
        float4 bb = *(const float4*)(bq + 4 * lg);
        uint2 pk;
        pk.x = cvt_pk_bf16(acc[0][0] + bb.x * LOG2E, acc[0][1] + bb.y * LOG2E);
        pk.y = cvt_pk_bf16(acc[0][2] + bb.z * LOG2E, acc[0][3] + bb.w * LOG2E);
        *(uint2*)&qT[((size_t)(b * HW + px)) * DQK + 4 * lg] = pk;
    }
    {
        float4 bb = *(const float4*)(bk + 4 * lg);
        uint2 pk;
        pk.x = cvt_pk_bf16(acc[1][0] + bb.x, acc[1][1] + bb.y);
        pk.y = cvt_pk_bf16(acc[1][2] + bb.z, acc[1][3] + bb.w);
        *(uint2*)&kT[((size_t)(b * HW + px)) * KTS + 4 * lg] = pk;
    }

    // ---- v: transpose through LDS (overlay x_l), then wide stores ----
    __syncthreads();   // all waves done reading x_l
    ushort* vt = (ushort*)x_l;              // [128c][VTP]
#pragma unroll
    for (int ot = 2; ot < 10; ot++) {
        const int cv = (ot - 2) * 16 + 4 * lg;
        const float4 bb = *(const float4*)(bv + cv);
        const unsigned w0 = cvt_pk_bf16(acc[ot][0] + bb.x, acc[ot][1] + bb.y);
        const unsigned w1 = cvt_pk_bf16(acc[ot][2] + bb.z, acc[ot][3] + bb.w);
        vt[(cv + 0) * VTP + px_loc] = (ushort)(w0 & 0xffff);
        vt[(cv + 1) * VTP + px_loc] = (ushort)(w0 >> 16);
        vt[(cv + 2) * VTP + px_loc] = (ushort)(w1 & 0xffff);
        vt[(cv + 3) * VTP + px_loc] = (ushort)(w1 >> 16);
    }
    __syncthreads();
    // read back b128 and store 16B coalesced: unit u -> (c = u>>3, px-octet = u&7)
#pragma unroll
    for (int i = 0; i < 4; i++) {
        const int u = t + 256 * i;
        const int c = u >> 3, oct = u & 7;
        const bf16x8 vv = *(const bf16x8*)&vt[c * VTP + oct * 8];
        *(bf16x8*)&v[((size_t)(b * CCH + c)) * HW + p0 + oct * 8] = vv;
    }
}

// ------------------------------------------------------------------
// Kernel B: flash attention, bf16 MFMA 16x16x32, KVBLK = 128.
// Same as R5 except kf B-frags load DIRECTLY from global (kT slice is
// 196KB/batch -> L2-resident under XCD swizzle): kT_l and its glds are
// deleted (LDS 54 -> 48KB, less addressing VALU, less LDS traffic).
// ------------------------------------------------------------------
__global__ __launch_bounds__(256) void attn_kernel(
    const ushort* __restrict__ qT, const ushort* __restrict__ kTg,
    const ushort* __restrict__ vg, const float* __restrict__ x,
    const float* __restrict__ gamma, float* __restrict__ out)
{
    // XCD swizzle: 512 = 8 XCDs x 64; each XCD gets one batch (K/V L2-resident)
    const int blk = ((blockIdx.x & 7) << 6) | (blockIdx.x >> 3);
    const int b   = blk >> 6;
    const int i0  = (blk & 63) << 6;
    const int t   = threadIdx.x;
    const int l   = t & 63;
    const int w   = t >> 6;
    const int lm  = l & 15;   // B-operand lane idx -> D col
    const int lg  = l >> 4;

    __shared__ __align__(16) ushort v_l[128 * 128];    // 32KB [c][128j] swizzled granules
    __shared__ __align__(16) ushort P_l[64 * 128];     // 16KB [i][128j] swizzled granules

    // ---- per-lane glds addresses (linear LDS dest; swizzled global src) ----
    const ushort* v_src[8];
    ushort*       v_dst[8];
#pragma unroll
    for (int it = 0; it < 8; it++) {
        const int idx = t + 256 * it;
        const int c   = idx >> 4;
        const int gs  = (idx & 15) ^ (c & 15);      // involutive granule swizzle
        v_src[it] = vg + ((size_t)(b * CCH + c)) * HW + gs * 8;
        v_dst[it] = &v_l[idx * 8];
    }

    // Q B-frag (log2e pre-folded): lane needs q[i = i0+16w+lm][d = lg*8..]; lg>=2 zero
    bf16x8 qf;
#pragma unroll
    for (int z = 0; z < 8; z++) qf[z] = 0;
    if (lg < 2)
        qf = *(const bf16x8*)(qT + ((size_t)(b * HW + i0 + 16 * w + lm)) * DQK + lg * 8);

    f32x4 zero4;
#pragma unroll
    for (int z = 0; z < 4; z++) zero4[z] = 0.f;

    f32x4 acc[8];
#pragma unroll
    for (int ct = 0; ct < 8; ct++) acc[ct] = zero4;

    float m_i = -1e30f, l_i = 0.f;

    for (int j0 = 0; j0 < HW; j0 += 128) {
        __syncthreads();   // previous tile fully consumed

        // ---- async stage: v (8 glds) ----
#pragma unroll
        for (int it = 0; it < 8; it++)
            glds16(v_src[it] + j0, v_dst[it]);

        // ---- S^T = mfma(K,Q): kf direct from global (L2-hit) ----
        const ushort* kbase = kTg + ((size_t)b * HW + j0) * KTS;
        f32x4 s[8];
#pragma unroll
        for (int jt = 0; jt < 8; jt++) {
            bf16x8 kf = {};
            if (lg < 2)    // exec-masked; k>=16 killed by qf zeros
                kf = *(const bf16x8*)(kbase + (jt * 16 + lm) * KTS + lg * 8);
            s[jt] = __builtin_amdgcn_mfma_f32_16x16x32_bf16(kf, qf, zero4, 0, 0, 0);
        }

        // ---- online softmax, one i per lane ----
        float mx = s[0][0];
#pragma unroll
        for (int jt = 0; jt < 8; jt++)
#pragma unroll
            for (int r = 0; r < 4; r++) mx = fmaxf(mx, s[jt][r]);
        mx = fmaxf(mx, __shfl_xor(mx, 16));
        mx = fmaxf(mx, __shfl_xor(mx, 32));

        float m_new, alpha;
        if (__all(mx - m_i <= 8.f)) {           // T13 defer-rescale
            m_new = m_i; alpha = 1.f;
        } else {
            m_new = fmaxf(m_i, mx);
            alpha = exp2f(m_i - m_new);
#pragma unroll
            for (int ct = 0; ct < 8; ct++) acc[ct] *= alpha;
        }

        float sum = 0.f;
        const int prow = (16 * w + lm) * 128;
#pragma unroll
        for (int jt = 0; jt < 8; jt++) {
            const float p0f = exp2f(s[jt][0] - m_new);
            const float p1f = exp2f(s[jt][1] - m_new);
            const float p2f = exp2f(s[jt][2] - m_new);
            const float p3f = exp2f(s[jt][3] - m_new);
            sum += (p0f + p1f) + (p2f + p3f);
            uint2 pk;
            pk.x = cvt_pk_bf16(p0f, p1f);
            pk.y = cvt_pk_bf16(p2f, p3f);
            const int g = (2 * jt + (lg >> 1)) ^ lm;   // swizzled granule
            *(uint2*)&P_l[prow + g * 8 + (lg & 1) * 4] = pk;
        }
        sum += __shfl_xor(sum, 16);
        sum += __shfl_xor(sum, 32);
        l_i = l_i * alpha + sum;
        m_i = m_new;

        __syncthreads();   // v_l staged (vmcnt drained) + all P writes visible

        // ---- PV: acc[ct] += v-tile(ct) . P^T ----
        __builtin_amdgcn_s_setprio(1);
#pragma unroll
        for (int ks = 0; ks < 4; ks++) {
            const int g = (4 * ks + lg) ^ lm;          // same swizzle both reads
            const bf16x8 pf = *(const bf16x8*)&P_l[prow + g * 8];
#pragma unroll
            for (int ct = 0; ct < 8; ct++) {
                const bf16x8 vf = *(const bf16x8*)&v_l[(ct * 16 + lm) * 128 + g * 8];
                acc[ct] = __builtin_amdgcn_mfma_f32_16x16x32_bf16(vf, pf, acc[ct], 0, 0, 0);
            }
        }
        __builtin_amdgcn_s_setprio(0);
    }

    // ---- epilogue: out = gamma * (acc / l) + x ----
    const float linv = 1.f / l_i;
    const float gm = gamma[0];
    const int i = 16 * w + lm;
#pragma unroll
    for (int ct = 0; ct < 8; ct++) {
#pragma unroll
        for (int r = 0; r < 4; r++) {
            const int c = ct * 16 + lg * 4 + r;
            const size_t off = ((size_t)(b * CCH + c)) * HW + i0 + i;
            out[off] = gm * (acc[ct][r] * linv) + x[off];
        }
    }
}

extern "C" void kernel_launch(void* const* d_in, const int* in_sizes, int n_in,
                              void* d_out, int out_size, void* d_ws, size_t ws_size,
                              hipStream_t stream)
{
    const float* x     = (const float*)d_in[0];
    const float* Wq    = (const float*)d_in[1];
    const float* bq    = (const float*)d_in[2];
    const float* Wk    = (const float*)d_in[3];
    const float* bk    = (const float*)d_in[4];
    const float* Wv    = (const float*)d_in[5];
    const float* bv    = (const float*)d_in[6];
    const float* gamma = (const float*)d_in[7];
    float* out = (float*)d_out;

    ushort* qT   = (ushort*)d_ws;                        // [8][4096][16]  bf16 (x log2e)
    ushort* kT   = qT + (size_t)BATCH * HW * DQK;        // [8][4096][KTS] bf16 padded
    ushort* v    = kT + (size_t)BATCH * HW * KTS;        // [8][128][4096] bf16
    ushort* Wpad = v  + (size_t)BATCH * CCH * HW;        // [WGRAN*8] bf16 padded

    prep_kernel<<<dim3(43), dim3(256), 0, stream>>>(Wq, Wk, Wv, Wpad);
    qkv_kernel<<<dim3(BATCH * (HW / 64)), dim3(256), 0, stream>>>(
        x, Wpad, bq, bk, bv, qT, kT, v);
    attn_kernel<<<dim3(BATCH * (HW / 64)), dim3(256), 0, stream>>>(
        qT, kT, v, x, gamma, out);
}